// Round 1
// baseline (569.856 us; speedup 1.0000x reference)
//
#include <hip/hip_runtime.h>
#include <hip/hip_bf16.h>

namespace {

constexpr int NB = 8;
constexpr int NV = 20000;
constexpr int NC = 256;
constexpr int NK = 128;
constexpr float LMBDA = 100.0f;

#define FMA4(acc, s, f) { (acc).x = fmaf((s),(f).x,(acc).x); (acc).y = fmaf((s),(f).y,(acc).y); \
                          (acc).z = fmaf((s),(f).z,(acc).z); (acc).w = fmaf((s),(f).w,(acc).w); }

// ---------------------------------------------------------------------------
// 1) Spectral projection: Out[b,k,c] = sum_v E[b,k,v] * F[b,v,c]
//    grid = (8 v-chunks of 2500, 2 c-halves of 128, 16 = b*2+side), 512 thr.
//    Each thread: 8k x 4c fp32 accumulators; LDS-staged Vt=16 slices with
//    register prefetch (global latency hidden under compute). Cross-chunk
//    reduction via atomicAdd into zero-initialized ws.
// ---------------------------------------------------------------------------
__global__ __launch_bounds__(512) void proj_kernel(
    const float* __restrict__ Ex, const float* __restrict__ Fx,
    const float* __restrict__ Ey, const float* __restrict__ Fy,
    float* __restrict__ A, float* __restrict__ Bm)
{
  const int chunk = blockIdx.x;      // 0..7
  const int ct    = blockIdx.y;      // 0..1
  const int b     = blockIdx.z >> 1;
  const int side  = blockIdx.z & 1;
  const float* __restrict__ E = (side ? Ey : Ex) + (size_t)b * NK * NV;
  const float* __restrict__ F = (side ? Fy : Fx) + (size_t)b * NV * NC;
  float* __restrict__ Out = (side ? Bm : A) + (size_t)b * NK * NC;
  const int c_base  = ct * 128;
  const int v_begin = chunk * 2500;

  __shared__ float Et[16][132];   // Et[j][k], padded
  __shared__ float Fs[16][132];   // Fs[j][c], padded

  const int tid = threadIdx.x;
  const int k0 = (tid >> 5) * 8;        // 16 k-groups
  const int c0 = (tid & 31) * 4;        // 32 c-groups
  const int ek = tid >> 2;              // E stage: row k
  const int ej0 = (tid & 3) * 4;        // E stage: 4 v's
  const int fj = tid >> 5;              // F stage: row v
  const int fc = (tid & 31) * 4;        // F stage: 4 c's

  const float* __restrict__ Erow = E + (size_t)ek * NV + v_begin;
  const float* __restrict__ Fcol = F + (size_t)v_begin * NC + c_base + fc;

  float4 acc[8];
#pragma unroll
  for (int u = 0; u < 8; u++) acc[u] = make_float4(0.f, 0.f, 0.f, 0.f);

  // clamped (always in-bounds) loads; zeroing predicates applied at LDS write
  int offE = ej0; if (offE > 2496) offE = 2496;
  float4 e4 = *(const float4*)(Erow + offE);
  int offF = fj; if (offF > 2499) offF = 2499;
  float4 f4 = *(const float4*)(Fcol + (size_t)offF * NC);

  for (int s0 = 0; s0 < 2500; s0 += 16) {
    const int rem = 2500 - s0;
    if (rem >= 16) {
      Et[ej0 + 0][ek] = e4.x;
      Et[ej0 + 1][ek] = e4.y;
      Et[ej0 + 2][ek] = e4.z;
      Et[ej0 + 3][ek] = e4.w;
      *(float4*)&Fs[fj][fc] = f4;
    } else {
      Et[ej0 + 0][ek] = (ej0 + 0 < rem) ? e4.x : 0.f;
      Et[ej0 + 1][ek] = (ej0 + 1 < rem) ? e4.y : 0.f;
      Et[ej0 + 2][ek] = (ej0 + 2 < rem) ? e4.z : 0.f;
      Et[ej0 + 3][ek] = (ej0 + 3 < rem) ? e4.w : 0.f;
      float4 fz = (fj < rem) ? f4 : make_float4(0.f, 0.f, 0.f, 0.f);
      *(float4*)&Fs[fj][fc] = fz;
    }
    __syncthreads();
    // prefetch next slice while computing this one
    if (s0 + 16 < 2500) {
      int oE = s0 + 16 + ej0; if (oE > 2496) oE = 2496;
      e4 = *(const float4*)(Erow + oE);
      int oF = s0 + 16 + fj; if (oF > 2499) oF = 2499;
      f4 = *(const float4*)(Fcol + (size_t)oF * NC);
    }
#pragma unroll
    for (int j = 0; j < 16; j++) {
      float4 fv = *(const float4*)&Fs[j][c0];
      float4 e0 = *(const float4*)&Et[j][k0];
      float4 e1 = *(const float4*)&Et[j][k0 + 4];
      FMA4(acc[0], e0.x, fv); FMA4(acc[1], e0.y, fv);
      FMA4(acc[2], e0.z, fv); FMA4(acc[3], e0.w, fv);
      FMA4(acc[4], e1.x, fv); FMA4(acc[5], e1.y, fv);
      FMA4(acc[6], e1.z, fv); FMA4(acc[7], e1.w, fv);
    }
    __syncthreads();
  }
#pragma unroll
  for (int u = 0; u < 8; u++) {
    float* dst = Out + (size_t)(k0 + u) * NC + c_base + c0;
    atomicAdd(dst + 0, acc[u].x);
    atomicAdd(dst + 1, acc[u].y);
    atomicAdd(dst + 2, acc[u].z);
    atomicAdd(dst + 3, acc[u].w);
  }
}

// ---------------------------------------------------------------------------
// 2) Gram: AAt[b,i,j] = sum_c A[b,i,c]A[b,j,c]; BAt[b,i,j] = sum_c B[b,i,c]A[b,j,c]
//    grid = (16 i-tiles of 8, 8 b), 256 thr. tid<128 -> AAt row-set, else BAt.
// ---------------------------------------------------------------------------
__global__ __launch_bounds__(256) void gram_kernel(
    const float* __restrict__ A, const float* __restrict__ Bm,
    float* __restrict__ AAt, float* __restrict__ BAt)
{
  const int i0 = blockIdx.x * 8;
  const int b  = blockIdx.y;
  __shared__ float Xi[16][260];
  const float* __restrict__ Ab = A  + (size_t)b * NK * NC;
  const float* __restrict__ Bb = Bm + (size_t)b * NK * NC;
  const int tid = threadIdx.x;
  for (int idx = tid; idx < 16 * 64; idx += 256) {
    int row = idx >> 6, c4 = idx & 63;
    const float* src = (row < 8) ? (Ab + (size_t)(i0 + row) * NC)
                                 : (Bb + (size_t)(i0 + row - 8) * NC);
    *(float4*)&Xi[row][c4 * 4] = *(const float4*)(src + c4 * 4);
  }
  __syncthreads();
  const int j = tid & 127;
  const int m = tid >> 7;   // 0: AAt, 1: BAt
  const float* __restrict__ Arow = Ab + (size_t)j * NC;
  float accv[8];
#pragma unroll
  for (int i = 0; i < 8; i++) accv[i] = 0.f;
  for (int c4 = 0; c4 < 64; c4++) {
    float4 a4 = *(const float4*)(Arow + c4 * 4);
#pragma unroll
    for (int i = 0; i < 8; i++) {
      float4 x4 = *(const float4*)&Xi[m * 8 + i][c4 * 4];
      accv[i] = fmaf(x4.x, a4.x, accv[i]);
      accv[i] = fmaf(x4.y, a4.y, accv[i]);
      accv[i] = fmaf(x4.z, a4.z, accv[i]);
      accv[i] = fmaf(x4.w, a4.w, accv[i]);
    }
  }
  float* Outp = (m ? BAt : AAt) + ((size_t)b * NK + i0) * NK + j;
#pragma unroll
  for (int i = 0; i < 8; i++) Outp[(size_t)i * NK] = accv[i];
}

// ---------------------------------------------------------------------------
// 3) Mask D[b,i,j]: g2 from evals_y[b,i], g1 from evals_x[b,j]; gamma=0.5
// ---------------------------------------------------------------------------
__global__ __launch_bounds__(256) void mask_kernel(
    const float* __restrict__ evx, const float* __restrict__ evy,
    float* __restrict__ Dm)
{
  const int b = blockIdx.x;
  const int tid = threadIdx.x;
  __shared__ float red[256];
  __shared__ float t1x[128], t2x[128], t1y[128], t2y[128];
  float v = (tid < 128) ? evx[b * 128 + tid] : evy[b * 128 + (tid - 128)];
  red[tid] = v;
  __syncthreads();
  for (int sft = 128; sft > 0; sft >>= 1) {
    if (tid < sft) red[tid] = fmaxf(red[tid], red[tid + sft]);
    __syncthreads();
  }
  const float inv_scale = 1.0f / red[0];
  if (tid < 128) {
    float e = evx[b * 128 + tid] * inv_scale;
    float g = sqrtf(e);
    float d = 1.f / (g * g + 1.f);
    t1x[tid] = g * d;  t2x[tid] = d;
  } else {
    int i = tid - 128;
    float e = evy[b * 128 + i] * inv_scale;
    float g = sqrtf(e);
    float d = 1.f / (g * g + 1.f);
    t1y[i] = g * d;  t2y[i] = d;
  }
  __syncthreads();
  float* __restrict__ Db = Dm + (size_t)b * NK * NK;
  for (int idx = tid; idx < NK * NK; idx += 256) {
    int i = idx >> 7, jj = idx & 127;
    float re = t1y[i] - t1x[jj];
    float im = t2y[i] - t2x[jj];
    Db[idx] = re * re + im * im;
  }
}

// ---------------------------------------------------------------------------
// 4) In-place Gauss-Jordan inversion (sweep) of SPD AAt[b] -> Sinv[b].
//    8 blocks x 512 thr; LDS [128][132] (dynamic, 67.6 KB). No pivoting
//    (SPD, cond ~ 30). Wave = 64 consecutive rows -> conflict-free b128.
// ---------------------------------------------------------------------------
__global__ __launch_bounds__(512) void invert_kernel(
    const float* __restrict__ AAt, float* __restrict__ Sinv)
{
  extern __shared__ float Ms[];  // [128][132]
  const int b = blockIdx.x;
  const int tid = threadIdx.x;
  const float* __restrict__ Sb = AAt + (size_t)b * NK * NK;
  for (int idx = tid; idx < NK * NK; idx += 512) {
    int r = idx >> 7, c = idx & 127;
    Ms[r * 132 + c] = Sb[idx];
  }
  const int r = tid & 127;
  const int h = tid >> 7;                 // 0..3 -> 32-col slab
  float* Mr = Ms + r * 132 + h * 32;
  for (int j = 0; j < NK; j++) {
    __syncthreads();
    const float invd = 1.f / Ms[j * 132 + j];
    if (r != j) {
      const float fi = Ms[r * 132 + j] * invd;
      const float* Mj = Ms + j * 132 + h * 32;
#pragma unroll
      for (int c4 = 0; c4 < 8; c4++) {
        float4 m4 = *(float4*)(Mr + c4 * 4);
        float4 p4 = *(const float4*)(Mj + c4 * 4);
        m4.x = fmaf(-fi, p4.x, m4.x);
        m4.y = fmaf(-fi, p4.y, m4.y);
        m4.z = fmaf(-fi, p4.z, m4.z);
        m4.w = fmaf(-fi, p4.w, m4.w);
        *(float4*)(Mr + c4 * 4) = m4;
      }
      if ((j >> 5) == h) Ms[r * 132 + j] = -fi;  // column sweep
    }
    __syncthreads();
    if (r == j) {                                 // row sweep (originals no longer needed)
      float* Mj2 = Ms + j * 132 + h * 32;
#pragma unroll
      for (int c = 0; c < 32; c++) Mj2[c] *= invd;
      if ((j >> 5) == h) Ms[j * 132 + j] = invd;
    }
  }
  __syncthreads();
  float* __restrict__ Ob = Sinv + (size_t)b * NK * NK;
  for (int idx = tid; idx < NK * NK; idx += 512) {
    int rr = idx >> 7, c = idx & 127;
    Ob[idx] = Ms[rr * 132 + c];
  }
}

// ---------------------------------------------------------------------------
// 5) Solve via Neumann fixed point (Sinv symmetric):
//    Yt = BAt * Sinv;  X <- Yt - (lambda*D o X) * Sinv  (2 iterations)
//    Cxy[b,i,:] = X[i,:].  8 blocks x 256 thr, LDS Sinv + Z (~133 KB).
// ---------------------------------------------------------------------------
__global__ __launch_bounds__(256) void solve_kernel(
    const float* __restrict__ Sinv, const float* __restrict__ BAt,
    const float* __restrict__ Dm, float* __restrict__ Cxy)
{
  extern __shared__ float sh[];
  float* SinvS = sh;               // [128][132]
  float* ZS    = sh + 128 * 132;   // [128][133]
  const int b = blockIdx.x;
  const int tid = threadIdx.x;
  const float* __restrict__ Sb = Sinv + (size_t)b * NK * NK;
  const float* __restrict__ Rb = BAt  + (size_t)b * NK * NK;
  const float* __restrict__ Db = Dm   + (size_t)b * NK * NK;
  for (int idx = tid; idx < NK * NK; idx += 256) {
    int r = idx >> 7, c = idx & 127;
    SinvS[r * 132 + c] = Sb[idx];
    ZS[r * 133 + c]    = Rb[idx];
  }
  __syncthreads();
  const int i0 = (tid >> 4) * 8;
  const int r0 = (tid & 15) * 8;
  float Y[8][8], X[8][8];
#pragma unroll
  for (int u = 0; u < 8; u++)
#pragma unroll
    for (int v = 0; v < 8; v++) Y[u][v] = 0.f;

  for (int c = 0; c < NK; c++) {           // Y = BAt * Sinv
    float4 s0 = *(const float4*)&SinvS[c * 132 + r0];
    float4 s1 = *(const float4*)&SinvS[c * 132 + r0 + 4];
#pragma unroll
    for (int u = 0; u < 8; u++) {
      float z = ZS[(i0 + u) * 133 + c];
      Y[u][0] = fmaf(z, s0.x, Y[u][0]);
      Y[u][1] = fmaf(z, s0.y, Y[u][1]);
      Y[u][2] = fmaf(z, s0.z, Y[u][2]);
      Y[u][3] = fmaf(z, s0.w, Y[u][3]);
      Y[u][4] = fmaf(z, s1.x, Y[u][4]);
      Y[u][5] = fmaf(z, s1.y, Y[u][5]);
      Y[u][6] = fmaf(z, s1.z, Y[u][6]);
      Y[u][7] = fmaf(z, s1.w, Y[u][7]);
    }
  }
#pragma unroll
  for (int u = 0; u < 8; u++)
#pragma unroll
    for (int v = 0; v < 8; v++) X[u][v] = Y[u][v];

  for (int it = 0; it < 2; it++) {
    __syncthreads();                        // all reads of ZS done
#pragma unroll
    for (int u = 0; u < 8; u++) {
      const float* drow = Db + (size_t)(i0 + u) * NK + r0;
      float* zrow = ZS + (i0 + u) * 133 + r0;
#pragma unroll
      for (int v = 0; v < 8; v++) zrow[v] = LMBDA * drow[v] * X[u][v];
    }
    __syncthreads();
#pragma unroll
    for (int u = 0; u < 8; u++)
#pragma unroll
      for (int v = 0; v < 8; v++) X[u][v] = Y[u][v];
    for (int c = 0; c < NK; c++) {          // X = Y - Z * Sinv
      float4 s0 = *(const float4*)&SinvS[c * 132 + r0];
      float4 s1 = *(const float4*)&SinvS[c * 132 + r0 + 4];
#pragma unroll
      for (int u = 0; u < 8; u++) {
        float z = ZS[(i0 + u) * 133 + c];
        X[u][0] = fmaf(-z, s0.x, X[u][0]);
        X[u][1] = fmaf(-z, s0.y, X[u][1]);
        X[u][2] = fmaf(-z, s0.z, X[u][2]);
        X[u][3] = fmaf(-z, s0.w, X[u][3]);
        X[u][4] = fmaf(-z, s1.x, X[u][4]);
        X[u][5] = fmaf(-z, s1.y, X[u][5]);
        X[u][6] = fmaf(-z, s1.z, X[u][6]);
        X[u][7] = fmaf(-z, s1.w, X[u][7]);
      }
    }
  }
  float* __restrict__ Ob = Cxy + ((size_t)b * NK + i0) * NK + r0;
#pragma unroll
  for (int u = 0; u < 8; u++) {
    float4 o0 = make_float4(X[u][0], X[u][1], X[u][2], X[u][3]);
    float4 o1 = make_float4(X[u][4], X[u][5], X[u][6], X[u][7]);
    *(float4*)(Ob + (size_t)u * NK)     = o0;
    *(float4*)(Ob + (size_t)u * NK + 4) = o1;
  }
}

} // anonymous namespace

extern "C" void kernel_launch(void* const* d_in, const int* in_sizes, int n_in,
                              void* d_out, int out_size, void* d_ws, size_t ws_size,
                              hipStream_t stream) {
  (void)in_sizes; (void)n_in; (void)out_size; (void)ws_size;
  const float* feat_x  = (const float*)d_in[0];
  const float* feat_y  = (const float*)d_in[1];
  const float* evals_x = (const float*)d_in[2];
  const float* evals_y = (const float*)d_in[3];
  const float* etx     = (const float*)d_in[4];
  const float* ety     = (const float*)d_in[5];
  float* out = (float*)d_out;
  float* ws  = (float*)d_ws;

  // ws layout (floats): A[8*128*256] | Bm[8*128*256] | AAt | BAt | D | Sinv  (4 MB total)
  float* A    = ws;
  float* Bm   = ws + 262144;
  float* AAt  = ws + 524288;
  float* BAt  = ws + 655360;
  float* Dm   = ws + 786432;
  float* Sinv = ws + 917504;

  // A/Bm are atomically accumulated -> zero-init each call
  hipMemsetAsync(A, 0, (size_t)524288 * sizeof(float), stream);

  hipFuncSetAttribute((const void*)invert_kernel,
                      hipFuncAttributeMaxDynamicSharedMemorySize, 128 * 132 * 4);
  hipFuncSetAttribute((const void*)solve_kernel,
                      hipFuncAttributeMaxDynamicSharedMemorySize, (128 * 132 + 128 * 133) * 4);

  proj_kernel<<<dim3(8, 2, 16), 512, 0, stream>>>(etx, feat_x, ety, feat_y, A, Bm);
  gram_kernel<<<dim3(16, 8), 256, 0, stream>>>(A, Bm, AAt, BAt);
  mask_kernel<<<dim3(8), 256, 0, stream>>>(evals_x, evals_y, Dm);
  invert_kernel<<<dim3(8), 512, 128 * 132 * 4, stream>>>(AAt, Sinv);
  solve_kernel<<<dim3(8), 256, (128 * 132 + 128 * 133) * 4, stream>>>(Sinv, BAt, Dm, out);
}

// Round 2
// 375.131 us; speedup vs baseline: 1.5191x; 1.5191x over previous
//
#include <hip/hip_runtime.h>
#include <hip/hip_bf16.h>

namespace {

constexpr int NB = 8;
constexpr int NV = 20000;
constexpr int NC = 256;
constexpr int NK = 128;
constexpr float LMBDA = 100.0f;
constexpr int KSTEP = 32;
constexpr int NSTEPS = 625;     // 20000 / 32 exactly
constexpr int CHUNKS = 16;      // v-chunks; chunk 0 gets 40 steps, rest 39

typedef __attribute__((ext_vector_type(8))) short bf16x8;
typedef __attribute__((ext_vector_type(4))) float f32x4;

__device__ __forceinline__ ushort f2bf(float x) {
  uint u = __float_as_uint(x);
  u += 0x7fffu + ((u >> 16) & 1u);
  return (ushort)(u >> 16);
}
__device__ __forceinline__ float bf2f(ushort h) { return __uint_as_float(((uint)h) << 16); }

// ---------------------------------------------------------------------------
// 1) Spectral projection via split-bf16 MFMA (hi*hi + hi*lo + lo*hi).
//    Tile 128k x 128c, KSTEP=32, 512 thr (8 waves as 2M x 4N, wave=64k x 32c).
//    LDS fragment-major: op[hl][frag][entry64][slot8] bf16; entry swizzled.
//    MODE 0: store fp32 partial per chunk (reduce pass sums). MODE 1: atomicAdd.
// ---------------------------------------------------------------------------
template <int MODE>
__global__ __launch_bounds__(512, 4) void proj_mfma(
    const float* __restrict__ Ex, const float* __restrict__ Fx,
    const float* __restrict__ Ey, const float* __restrict__ Fy,
    float* __restrict__ A, float* __restrict__ Bm, float* __restrict__ P)
{
  const int chunk = blockIdx.x;            // 0..15
  const int ct    = blockIdx.y;            // 0..1 (c half)
  const int bs    = blockIdx.z;            // b*2+side
  const int b     = bs >> 1;
  const int side  = bs & 1;
  const float* __restrict__ E = (side ? Ey : Ex) + (size_t)b * NK * NV;
  const float* __restrict__ F = (side ? Fy : Fx) + (size_t)b * NV * NC;
  float* __restrict__ Out = (side ? Bm : A) + (size_t)b * NK * NC;
  const int cb = ct * 128;

  const int start = chunk * 39 + (chunk > 0 ? 1 : 0);
  const int nsteps = 39 + (chunk == 0 ? 1 : 0);
  const int v0 = start * KSTEP;

  // LDS: [hi/lo][frag 8][entry 64][slot 8] bf16 (ushort) = 16 KB each
  __shared__ __align__(16) ushort AH[2][8][64][8];
  __shared__ __align__(16) ushort BH[2][8][64][8];

  const int tid  = threadIdx.x;
  const int lane = tid & 63;
  const int w    = tid >> 6;
  const int wm   = w >> 2;       // 0..1 (64-row group)
  const int wn   = w & 3;        // 0..3 (32-col group)
  const int lrow = lane >> 4;    // 0..3
  const int lcol = lane & 15;

  // --- staging thread mappings ---
  // E: thread -> row k = tid>>2 (0..127), vg = tid&3, 8 consecutive v
  const int ek  = tid >> 2;
  const int evg = tid & 3;
  const int ef  = ek >> 4;
  const int entE = (((ek & 15) + evg * 4) & 15) + evg * 16;
  const float* Eptr = E + (size_t)ek * NV + v0 + evg * 8;

  // F: thread -> v-pair p = tid&15 (rows 2p,2p+1), c0 = (tid>>4)*4
  const int fp  = tid & 15;
  const int fc0 = (tid >> 4) * 4;         // 0..124 within half
  const int fcg = fc0 >> 4;               // 0..7
  const int fclow = fc0 & 15;             // 0,4,8,12
  const int fvg = fp >> 2;
  const int fsp = fp & 3;                 // slot-pair word
  const float* Fptr = F + (size_t)(v0 + 2 * fp) * NC + cb + fc0;

  f32x4 acc[4][2];
#pragma unroll
  for (int fi = 0; fi < 4; fi++)
#pragma unroll
    for (int ni = 0; ni < 2; ni++) acc[fi][ni] = (f32x4)0.f;

  // operand-read entries (swizzles must match writers)
  const int entA = (((lcol) + lrow * 4) & 15) + lrow * 16;

  float4 e0 = *(const float4*)(Eptr);
  float4 e1 = *(const float4*)(Eptr + 4);
  float4 f0 = *(const float4*)(Fptr);
  float4 f1 = *(const float4*)(Fptr + NC);

  for (int s = 0; s < nsteps; s++) {
    // ---- convert + write LDS from registers ----
    {
      const float v[8] = {e0.x, e0.y, e0.z, e0.w, e1.x, e1.y, e1.z, e1.w};
      uint hiw[4], low[4];
#pragma unroll
      for (int i = 0; i < 4; i++) {
        float a = v[2 * i], c = v[2 * i + 1];
        ushort ha = f2bf(a), hc = f2bf(c);
        hiw[i] = (uint)ha | ((uint)hc << 16);
        low[i] = (uint)f2bf(a - bf2f(ha)) | ((uint)f2bf(c - bf2f(hc)) << 16);
      }
      *(uint4*)&AH[0][ef][entE][0] = make_uint4(hiw[0], hiw[1], hiw[2], hiw[3]);
      *(uint4*)&AH[1][ef][entE][0] = make_uint4(low[0], low[1], low[2], low[3]);

      const float* fa = (const float*)&f0;
      const float* fb = (const float*)&f1;
#pragma unroll
      for (int j = 0; j < 4; j++) {
        int ent = ((fclow + j + fcg) & 15) + fvg * 16;
        float a = fa[j], c = fb[j];
        ushort ha = f2bf(a), hc = f2bf(c);
        *(uint*)&BH[0][fcg][ent][2 * fsp] = (uint)ha | ((uint)hc << 16);
        *(uint*)&BH[1][fcg][ent][2 * fsp] =
            (uint)f2bf(a - bf2f(ha)) | ((uint)f2bf(c - bf2f(hc)) << 16);
      }
    }
    __syncthreads();

    // ---- prefetch next step ----
    if (s + 1 < nsteps) {
      Eptr += KSTEP;
      Fptr += (size_t)KSTEP * NC;
      e0 = *(const float4*)(Eptr);
      e1 = *(const float4*)(Eptr + 4);
      f0 = *(const float4*)(Fptr);
      f1 = *(const float4*)(Fptr + NC);
    }

    // ---- MFMA ----
    {
      bf16x8 bHf[2], bLf[2];
#pragma unroll
      for (int ni = 0; ni < 2; ni++) {
        int cg = wn * 2 + ni;
        int entB = ((lcol + cg) & 15) + lrow * 16;
        bHf[ni] = *(const bf16x8*)&BH[0][cg][entB][0];
        bLf[ni] = *(const bf16x8*)&BH[1][cg][entB][0];
      }
#pragma unroll
      for (int fi = 0; fi < 4; fi++) {
        bf16x8 aH = *(const bf16x8*)&AH[0][wm * 4 + fi][entA][0];
        bf16x8 aL = *(const bf16x8*)&AH[1][wm * 4 + fi][entA][0];
#pragma unroll
        for (int ni = 0; ni < 2; ni++) {
          acc[fi][ni] = __builtin_amdgcn_mfma_f32_16x16x32_bf16(aH, bHf[ni], acc[fi][ni], 0, 0, 0);
          acc[fi][ni] = __builtin_amdgcn_mfma_f32_16x16x32_bf16(aH, bLf[ni], acc[fi][ni], 0, 0, 0);
          acc[fi][ni] = __builtin_amdgcn_mfma_f32_16x16x32_bf16(aL, bHf[ni], acc[fi][ni], 0, 0, 0);
        }
      }
    }
    __syncthreads();
  }

  // ---- epilogue: C/D layout col=lane&15, row=(lane>>4)*4+reg ----
#pragma unroll
  for (int fi = 0; fi < 4; fi++) {
#pragma unroll
    for (int ni = 0; ni < 2; ni++) {
      const float* av = (const float*)&acc[fi][ni];
#pragma unroll
      for (int q = 0; q < 4; q++) {
        int row = wm * 64 + fi * 16 + lrow * 4 + q;
        int col = cb + wn * 32 + ni * 16 + lcol;
        if (MODE == 0) {
          P[(((size_t)chunk * 16 + bs) * NK + row) * NC + col] = av[q];
        } else {
          atomicAdd(&Out[(size_t)row * NC + col], av[q]);
        }
      }
    }
  }
}

// Sum the 16 chunk-partials into A|Bm (which are contiguous at AB).
__global__ __launch_bounds__(256) void reduce_kernel(
    const float* __restrict__ P, float* __restrict__ AB)
{
  const int g = blockIdx.x * 256 + threadIdx.x;   // 0..131071 (float4 index)
  const int bsi = g >> 13;                        // 0..15
  const int rem4 = g & 8191;
  const int side = bsi & 1, b = bsi >> 1;
  float4 s = make_float4(0.f, 0.f, 0.f, 0.f);
#pragma unroll
  for (int ch = 0; ch < CHUNKS; ch++) {
    float4 v = *(const float4*)(P + (((size_t)ch * 16 + bsi) * 8192 + rem4) * 4);
    s.x += v.x; s.y += v.y; s.z += v.z; s.w += v.w;
  }
  *(float4*)(AB + ((size_t)side * 262144 + (size_t)b * 8192 * 4 + (size_t)rem4 * 4)) = s;
}

// ---------------------------------------------------------------------------
// 2) Gram: AAt[b,i,j] = sum_c A[b,i,c]A[b,j,c]; BAt[b,i,j] = sum_c B[b,i,c]A[b,j,c]
// ---------------------------------------------------------------------------
__global__ __launch_bounds__(256) void gram_kernel(
    const float* __restrict__ A, const float* __restrict__ Bm,
    float* __restrict__ AAt, float* __restrict__ BAt)
{
  const int i0 = blockIdx.x * 8;
  const int b  = blockIdx.y;
  __shared__ float Xi[16][260];
  const float* __restrict__ Ab = A  + (size_t)b * NK * NC;
  const float* __restrict__ Bb = Bm + (size_t)b * NK * NC;
  const int tid = threadIdx.x;
  for (int idx = tid; idx < 16 * 64; idx += 256) {
    int row = idx >> 6, c4 = idx & 63;
    const float* src = (row < 8) ? (Ab + (size_t)(i0 + row) * NC)
                                 : (Bb + (size_t)(i0 + row - 8) * NC);
    *(float4*)&Xi[row][c4 * 4] = *(const float4*)(src + c4 * 4);
  }
  __syncthreads();
  const int j = tid & 127;
  const int m = tid >> 7;   // 0: AAt, 1: BAt
  const float* __restrict__ Arow = Ab + (size_t)j * NC;
  float accv[8];
#pragma unroll
  for (int i = 0; i < 8; i++) accv[i] = 0.f;
  for (int c4 = 0; c4 < 64; c4++) {
    float4 a4 = *(const float4*)(Arow + c4 * 4);
#pragma unroll
    for (int i = 0; i < 8; i++) {
      float4 x4 = *(const float4*)&Xi[m * 8 + i][c4 * 4];
      accv[i] = fmaf(x4.x, a4.x, accv[i]);
      accv[i] = fmaf(x4.y, a4.y, accv[i]);
      accv[i] = fmaf(x4.z, a4.z, accv[i]);
      accv[i] = fmaf(x4.w, a4.w, accv[i]);
    }
  }
  float* Outp = (m ? BAt : AAt) + ((size_t)b * NK + i0) * NK + j;
#pragma unroll
  for (int i = 0; i < 8; i++) Outp[(size_t)i * NK] = accv[i];
}

// ---------------------------------------------------------------------------
// 3) Mask D[b,i,j]
// ---------------------------------------------------------------------------
__global__ __launch_bounds__(256) void mask_kernel(
    const float* __restrict__ evx, const float* __restrict__ evy,
    float* __restrict__ Dm)
{
  const int b = blockIdx.x;
  const int tid = threadIdx.x;
  __shared__ float red[256];
  __shared__ float t1x[128], t2x[128], t1y[128], t2y[128];
  float v = (tid < 128) ? evx[b * 128 + tid] : evy[b * 128 + (tid - 128)];
  red[tid] = v;
  __syncthreads();
  for (int sft = 128; sft > 0; sft >>= 1) {
    if (tid < sft) red[tid] = fmaxf(red[tid], red[tid + sft]);
    __syncthreads();
  }
  const float inv_scale = 1.0f / red[0];
  if (tid < 128) {
    float e = evx[b * 128 + tid] * inv_scale;
    float g = sqrtf(e);
    float d = 1.f / (g * g + 1.f);
    t1x[tid] = g * d;  t2x[tid] = d;
  } else {
    int i = tid - 128;
    float e = evy[b * 128 + i] * inv_scale;
    float g = sqrtf(e);
    float d = 1.f / (g * g + 1.f);
    t1y[i] = g * d;  t2y[i] = d;
  }
  __syncthreads();
  float* __restrict__ Db = Dm + (size_t)b * NK * NK;
  for (int idx = tid; idx < NK * NK; idx += 256) {
    int i = idx >> 7, jj = idx & 127;
    float re = t1y[i] - t1x[jj];
    float im = t2y[i] - t2x[jj];
    Db[idx] = re * re + im * im;
  }
}

// ---------------------------------------------------------------------------
// 4) In-place Gauss-Jordan inversion of SPD AAt[b] -> Sinv[b].
// ---------------------------------------------------------------------------
__global__ __launch_bounds__(512) void invert_kernel(
    const float* __restrict__ AAt, float* __restrict__ Sinv)
{
  extern __shared__ float Ms[];  // [128][132]
  const int b = blockIdx.x;
  const int tid = threadIdx.x;
  const float* __restrict__ Sb = AAt + (size_t)b * NK * NK;
  for (int idx = tid; idx < NK * NK; idx += 512) {
    int r = idx >> 7, c = idx & 127;
    Ms[r * 132 + c] = Sb[idx];
  }
  const int r = tid & 127;
  const int h = tid >> 7;                 // 0..3 -> 32-col slab
  float* Mr = Ms + r * 132 + h * 32;
  for (int j = 0; j < NK; j++) {
    __syncthreads();
    const float invd = 1.f / Ms[j * 132 + j];
    if (r != j) {
      const float fi = Ms[r * 132 + j] * invd;
      const float* Mj = Ms + j * 132 + h * 32;
#pragma unroll
      for (int c4 = 0; c4 < 8; c4++) {
        float4 m4 = *(float4*)(Mr + c4 * 4);
        float4 p4 = *(const float4*)(Mj + c4 * 4);
        m4.x = fmaf(-fi, p4.x, m4.x);
        m4.y = fmaf(-fi, p4.y, m4.y);
        m4.z = fmaf(-fi, p4.z, m4.z);
        m4.w = fmaf(-fi, p4.w, m4.w);
        *(float4*)(Mr + c4 * 4) = m4;
      }
      if ((j >> 5) == h) Ms[r * 132 + j] = -fi;
    }
    __syncthreads();
    if (r == j) {
      float* Mj2 = Ms + j * 132 + h * 32;
#pragma unroll
      for (int c = 0; c < 32; c++) Mj2[c] *= invd;
      if ((j >> 5) == h) Ms[j * 132 + j] = invd;
    }
  }
  __syncthreads();
  float* __restrict__ Ob = Sinv + (size_t)b * NK * NK;
  for (int idx = tid; idx < NK * NK; idx += 512) {
    int rr = idx >> 7, c = idx & 127;
    Ob[idx] = Ms[rr * 132 + c];
  }
}

// ---------------------------------------------------------------------------
// 5) Solve via Neumann fixed point (2 iterations).
// ---------------------------------------------------------------------------
__global__ __launch_bounds__(256) void solve_kernel(
    const float* __restrict__ Sinv, const float* __restrict__ BAt,
    const float* __restrict__ Dm, float* __restrict__ Cxy)
{
  extern __shared__ float sh[];
  float* SinvS = sh;               // [128][132]
  float* ZS    = sh + 128 * 132;   // [128][133]
  const int b = blockIdx.x;
  const int tid = threadIdx.x;
  const float* __restrict__ Sb = Sinv + (size_t)b * NK * NK;
  const float* __restrict__ Rb = BAt  + (size_t)b * NK * NK;
  const float* __restrict__ Db = Dm   + (size_t)b * NK * NK;
  for (int idx = tid; idx < NK * NK; idx += 256) {
    int r = idx >> 7, c = idx & 127;
    SinvS[r * 132 + c] = Sb[idx];
    ZS[r * 133 + c]    = Rb[idx];
  }
  __syncthreads();
  const int i0 = (tid >> 4) * 8;
  const int r0 = (tid & 15) * 8;
  float Y[8][8], X[8][8];
#pragma unroll
  for (int u = 0; u < 8; u++)
#pragma unroll
    for (int v = 0; v < 8; v++) Y[u][v] = 0.f;

  for (int c = 0; c < NK; c++) {
    float4 s0 = *(const float4*)&SinvS[c * 132 + r0];
    float4 s1 = *(const float4*)&SinvS[c * 132 + r0 + 4];
#pragma unroll
    for (int u = 0; u < 8; u++) {
      float z = ZS[(i0 + u) * 133 + c];
      Y[u][0] = fmaf(z, s0.x, Y[u][0]);
      Y[u][1] = fmaf(z, s0.y, Y[u][1]);
      Y[u][2] = fmaf(z, s0.z, Y[u][2]);
      Y[u][3] = fmaf(z, s0.w, Y[u][3]);
      Y[u][4] = fmaf(z, s1.x, Y[u][4]);
      Y[u][5] = fmaf(z, s1.y, Y[u][5]);
      Y[u][6] = fmaf(z, s1.z, Y[u][6]);
      Y[u][7] = fmaf(z, s1.w, Y[u][7]);
    }
  }
#pragma unroll
  for (int u = 0; u < 8; u++)
#pragma unroll
    for (int v = 0; v < 8; v++) X[u][v] = Y[u][v];

  for (int it = 0; it < 2; it++) {
    __syncthreads();
#pragma unroll
    for (int u = 0; u < 8; u++) {
      const float* drow = Db + (size_t)(i0 + u) * NK + r0;
      float* zrow = ZS + (i0 + u) * 133 + r0;
#pragma unroll
      for (int v = 0; v < 8; v++) zrow[v] = LMBDA * drow[v] * X[u][v];
    }
    __syncthreads();
#pragma unroll
    for (int u = 0; u < 8; u++)
#pragma unroll
      for (int v = 0; v < 8; v++) X[u][v] = Y[u][v];
    for (int c = 0; c < NK; c++) {
      float4 s0 = *(const float4*)&SinvS[c * 132 + r0];
      float4 s1 = *(const float4*)&SinvS[c * 132 + r0 + 4];
#pragma unroll
      for (int u = 0; u < 8; u++) {
        float z = ZS[(i0 + u) * 133 + c];
        X[u][0] = fmaf(-z, s0.x, X[u][0]);
        X[u][1] = fmaf(-z, s0.y, X[u][1]);
        X[u][2] = fmaf(-z, s0.z, X[u][2]);
        X[u][3] = fmaf(-z, s0.w, X[u][3]);
        X[u][4] = fmaf(-z, s1.x, X[u][4]);
        X[u][5] = fmaf(-z, s1.y, X[u][5]);
        X[u][6] = fmaf(-z, s1.z, X[u][6]);
        X[u][7] = fmaf(-z, s1.w, X[u][7]);
      }
    }
  }
  float* __restrict__ Ob = Cxy + ((size_t)b * NK + i0) * NK + r0;
#pragma unroll
  for (int u = 0; u < 8; u++) {
    float4 o0 = make_float4(X[u][0], X[u][1], X[u][2], X[u][3]);
    float4 o1 = make_float4(X[u][4], X[u][5], X[u][6], X[u][7]);
    *(float4*)(Ob + (size_t)u * NK)     = o0;
    *(float4*)(Ob + (size_t)u * NK + 4) = o1;
  }
}

} // anonymous namespace

extern "C" void kernel_launch(void* const* d_in, const int* in_sizes, int n_in,
                              void* d_out, int out_size, void* d_ws, size_t ws_size,
                              hipStream_t stream) {
  (void)in_sizes; (void)n_in; (void)out_size;
  const float* feat_x  = (const float*)d_in[0];
  const float* feat_y  = (const float*)d_in[1];
  const float* evals_x = (const float*)d_in[2];
  const float* evals_y = (const float*)d_in[3];
  const float* etx     = (const float*)d_in[4];
  const float* ety     = (const float*)d_in[5];
  float* out = (float*)d_out;
  float* ws  = (float*)d_ws;

  // ws layout (floats): A[262144] Bm[262144] AAt BAt Dm Sinv (1,048,576 fl = 4MB)
  // then partials P[16][16][128][256] (8,388,608 fl = 33.5MB) if ws allows.
  float* A    = ws;
  float* Bm   = ws + 262144;
  float* AAt  = ws + 524288;
  float* BAt  = ws + 655360;
  float* Dm   = ws + 786432;
  float* Sinv = ws + 917504;
  float* P    = ws + 1048576;

  const bool use_partial = ws_size >= (size_t)(1048576 + 8388608) * 4;

  hipFuncSetAttribute((const void*)invert_kernel,
                      hipFuncAttributeMaxDynamicSharedMemorySize, 128 * 132 * 4);
  hipFuncSetAttribute((const void*)solve_kernel,
                      hipFuncAttributeMaxDynamicSharedMemorySize, (128 * 132 + 128 * 133) * 4);

  if (use_partial) {
    proj_mfma<0><<<dim3(CHUNKS, 2, 16), 512, 0, stream>>>(etx, feat_x, ety, feat_y, A, Bm, P);
    reduce_kernel<<<dim3(512), 256, 0, stream>>>(P, ws);
  } else {
    hipMemsetAsync(A, 0, (size_t)524288 * sizeof(float), stream);
    proj_mfma<1><<<dim3(CHUNKS, 2, 16), 512, 0, stream>>>(etx, feat_x, ety, feat_y, A, Bm, P);
  }
  gram_kernel<<<dim3(16, 8), 256, 0, stream>>>(A, Bm, AAt, BAt);
  mask_kernel<<<dim3(8), 256, 0, stream>>>(evals_x, evals_y, Dm);
  invert_kernel<<<dim3(8), 512, 128 * 132 * 4, stream>>>(AAt, Sinv);
  solve_kernel<<<dim3(8), 256, (128 * 132 + 128 * 133) * 4, stream>>>(Sinv, BAt, Dm, out);
}